// Round 13
// baseline (69.890 us; speedup 1.0000x reference)
//
#include <hip/hip_runtime.h>

constexpr int TPB = 256;
constexpr int PAIRS_PER_BLOCK = 32;   // 8 lanes per pair, 256 threads

__device__ __forceinline__ float fast_tanh(float v) {
    // tanh(x) = 1 - 2/(exp(2x)+1); exact at +/-inf, ~ulp-level error
    float ex = __expf(2.0f * v);
    return 1.0f - 2.0f * __builtin_amdgcn_rcpf(ex + 1.0f);
}

template <int CTRL>
__device__ __forceinline__ float dppadd(float x) {
    return x + __int_as_float(__builtin_amdgcn_update_dpp(
        0, __float_as_int(x), CTRL, 0xf, 0xf, true));
}
template <int CTRL>
__device__ __forceinline__ float dppmax(float x) {
    return fmaxf(x, __int_as_float(__builtin_amdgcn_update_dpp(
        0, __float_as_int(x), CTRL, 0xf, 0xf, true)));
}

// all-lanes reduce within a 16-lane DPP row (used by pack + f32 fallback)
__device__ __forceinline__ float rowsum16(float x) {
    x = dppadd<0x128>(x); x = dppadd<0x124>(x);
    x = dppadd<0x122>(x); x = dppadd<0x121>(x);
    return x;
}
__device__ __forceinline__ float rowmax16(float x) {
    x = dppmax<0x128>(x); x = dppmax<0x124>(x);
    x = dppmax<0x122>(x); x = dppmax<0x121>(x);
    return x;
}

// all-reduce over a pair's 8 lanes laid out as {quad q, quad q+2} of a 16-lane
// row (round-6 proven): row_ror:8 merges the pair's two quads, then two
// quad_perm rotations finish the 4-lane all-reduce.
__device__ __forceinline__ float sum8(float x) {
    x = dppadd<0x128>(x);  // row_ror:8
    x = dppadd<0x39>(x);   // quad_perm [1,2,3,0]
    x = dppadd<0x4E>(x);   // quad_perm [2,3,0,1]
    return x;
}

__device__ __forceinline__ float2 unpack_q(unsigned int w) {
    // low/high int16 -> float (int-valued)
    return make_float2((float)((int)(w << 16) >> 16), (float)((int)w >> 16));
}

// ---- pack kernel: x (N,4,32) f32 -> int16 with per-node scale --------------
// Layout (unchanged from round 11): xq[node*16 + l] = uint4 of w[d]=cols
// {2l,2l+1}, d=0..3. For the P=8 main kernel, slot s reads lanes 2s,2s+1 ->
// two CONTIGUOUS uint4s covering cols {4s..4s+3}.
__global__ __launch_bounds__(TPB) void pack_q16_kernel(
    const float* __restrict__ x, uint4* __restrict__ xq,
    float* __restrict__ xscale, int N)
{
    const int tid  = blockIdx.x * TPB + threadIdx.x;
    const int node = tid >> 4, l = tid & 15;
    if (node >= N) return;
    const float* xr = x + (size_t)node * 128 + 2 * l;
    float2 f[4]; float m = 0.f;
    #pragma unroll
    for (int d = 0; d < 4; ++d) {
        f[d] = *(const float2*)(xr + d * 32);       // coalesced 8B/lane
        m = fmaxf(m, fmaxf(fabsf(f[d].x), fabsf(f[d].y)));
    }
    m = rowmax16(m);                                 // node absmax (all 16 lanes)
    const float inv = m > 0.f ? 32767.0f / m : 0.f;
    unsigned int w[4];
    #pragma unroll
    for (int d = 0; d < 4; ++d) {
        int ix = (int)rintf(f[d].x * inv);
        int iy = (int)rintf(f[d].y * inv);
        w[d] = ((unsigned int)ix & 0xFFFFu) | ((unsigned int)iy << 16);
    }
    xq[(size_t)node * 16 + l] = make_uint4(w[0], w[1], w[2], w[3]);  // coalesced
    if (l == 0) xscale[node] = m * (1.0f / 32767.0f);
}

// ---- main kernel: P=8 lanes/pair, int16 x ----------------------------------
//   Z = (su*M1)*U_int - (sv*M2)*V_int ; sims1 = 2*su*(Z U^T); sims2 = -2*sv*(Z V^T)
//   out[e] = tanh(W1 @ vec(sims_e) + b1)
// Lane slot owns h-cols [4*slot, 4*slot+4); lane owns outputs {2*slot, 2*slot+1}.
__global__ __launch_bounds__(TPB) void sheaf_q8_kernel(
    const uint4* __restrict__ xq,         // (N, 16) packed int16
    const float* __restrict__ xscale,     // (N,)
    const float* __restrict__ Maps,       // (E, 4, 4)
    const float* __restrict__ W1,         // (16, 16)
    const float* __restrict__ b1,         // (16,)
    const int*   __restrict__ edge_index, // (2, E)
    const int*   __restrict__ opp_idx,    // (E,)
    float*       __restrict__ out,        // (E, 4, 4)
    int E, int EHALF)
{
    const int tid    = threadIdx.x;
    const int lane16 = tid & 15;
    const int row16  = tid >> 4;
    const int pinr   = (lane16 >> 2) & 1;                         // pair within row
    const int slot   = (lane16 & 3) | (((lane16 >> 3) & 1) << 2); // 0..7 h-chunk
    const int pair   = blockIdx.x * PAIRS_PER_BLOCK + row16 * 2 + pinr;
    if (pair >= EHALF) return;   // uniform across the pair's 8 lanes

    const int s  = edge_index[pair];
    const int t  = edge_index[E + pair];
    const int e2 = opp_idx[pair];

    // two contiguous uint4 per node per lane: cols {4s,4s+1} then {4s+2,4s+3}
    const uint4* pu = xq + (size_t)s * 16 + 2 * slot;
    const uint4* pv = xq + (size_t)t * 16 + 2 * slot;
    const uint4 quA = pu[0], quB = pu[1];
    const uint4 qvA = pv[0], qvB = pv[1];
    const float su = xscale[s];
    const float sv = xscale[t];

    // unpack to int-valued float4 rows u[d] = cols 4s..4s+3 of row d
    float4 u[4], v[4];
    {
        float2 a, b;
        a = unpack_q(quA.x); b = unpack_q(quB.x); u[0] = make_float4(a.x, a.y, b.x, b.y);
        a = unpack_q(quA.y); b = unpack_q(quB.y); u[1] = make_float4(a.x, a.y, b.x, b.y);
        a = unpack_q(quA.z); b = unpack_q(quB.z); u[2] = make_float4(a.x, a.y, b.x, b.y);
        a = unpack_q(quA.w); b = unpack_q(quB.w); u[3] = make_float4(a.x, a.y, b.x, b.y);
        a = unpack_q(qvA.x); b = unpack_q(qvB.x); v[0] = make_float4(a.x, a.y, b.x, b.y);
        a = unpack_q(qvA.y); b = unpack_q(qvB.y); v[1] = make_float4(a.x, a.y, b.x, b.y);
        a = unpack_q(qvA.z); b = unpack_q(qvB.z); v[2] = make_float4(a.x, a.y, b.x, b.y);
        a = unpack_q(qvA.w); b = unpack_q(qvB.w); v[3] = make_float4(a.x, a.y, b.x, b.y);
    }

    // lane's two W1 rows (outputs 2*slot, 2*slot+1) + biases
    const int p0 = 2 * slot;
    float wA[16], wB[16];
    {
        const float4* WpA = (const float4*)(W1 + p0 * 16);
        const float4* WpB = (const float4*)(W1 + (p0 + 1) * 16);
        #pragma unroll
        for (int q4 = 0; q4 < 4; ++q4) {
            float4 a = WpA[q4], b = WpB[q4];
            wA[q4*4+0] = a.x; wA[q4*4+1] = a.y; wA[q4*4+2] = a.z; wA[q4*4+3] = a.w;
            wB[q4*4+0] = b.x; wB[q4*4+1] = b.y; wB[q4*4+2] = b.z; wB[q4*4+3] = b.w;
        }
    }
    const float2 bb = *(const float2*)(b1 + p0);

    const float4* M1p = (const float4*)(Maps + (size_t)pair * 16);
    const float4* M2p = (const float4*)(Maps + (size_t)e2   * 16);

    // fused: per (i,k), reduce over the pair's 8 lanes then fma into 4 outputs
    float d1a = 0.f, d1b = 0.f, d2a = 0.f, d2b = 0.f;
    #pragma unroll
    for (int i = 0; i < 4; ++i) {
        // scale-folded Maps rows: su*M1[i,:], sv*M2[i,:]
        float4 m1 = M1p[i], m2 = M2p[i];
        m1.x *= su; m1.y *= su; m1.z *= su; m1.w *= su;
        m2.x *= sv; m2.y *= sv; m2.z *= sv; m2.w *= sv;

        // Z row i over the lane's 4 h-cols (int basis)
        float4 zi;
        zi.x = m1.x * u[0].x;            zi.y = m1.x * u[0].y;
        zi.z = m1.x * u[0].z;            zi.w = m1.x * u[0].w;
        zi.x = fmaf(m1.y, u[1].x, zi.x); zi.y = fmaf(m1.y, u[1].y, zi.y);
        zi.z = fmaf(m1.y, u[1].z, zi.z); zi.w = fmaf(m1.y, u[1].w, zi.w);
        zi.x = fmaf(m1.z, u[2].x, zi.x); zi.y = fmaf(m1.z, u[2].y, zi.y);
        zi.z = fmaf(m1.z, u[2].z, zi.z); zi.w = fmaf(m1.z, u[2].w, zi.w);
        zi.x = fmaf(m1.w, u[3].x, zi.x); zi.y = fmaf(m1.w, u[3].y, zi.y);
        zi.z = fmaf(m1.w, u[3].z, zi.z); zi.w = fmaf(m1.w, u[3].w, zi.w);
        zi.x = fmaf(-m2.x, v[0].x, zi.x); zi.y = fmaf(-m2.x, v[0].y, zi.y);
        zi.z = fmaf(-m2.x, v[0].z, zi.z); zi.w = fmaf(-m2.x, v[0].w, zi.w);
        zi.x = fmaf(-m2.y, v[1].x, zi.x); zi.y = fmaf(-m2.y, v[1].y, zi.y);
        zi.z = fmaf(-m2.y, v[1].z, zi.z); zi.w = fmaf(-m2.y, v[1].w, zi.w);
        zi.x = fmaf(-m2.z, v[2].x, zi.x); zi.y = fmaf(-m2.z, v[2].y, zi.y);
        zi.z = fmaf(-m2.z, v[2].z, zi.z); zi.w = fmaf(-m2.z, v[2].w, zi.w);
        zi.x = fmaf(-m2.w, v[3].x, zi.x); zi.y = fmaf(-m2.w, v[3].y, zi.y);
        zi.z = fmaf(-m2.w, v[3].z, zi.z); zi.w = fmaf(-m2.w, v[3].w, zi.w);

        #pragma unroll
        for (int k = 0; k < 4; ++k) {
            float pa = zi.x * u[k].x;
            pa = fmaf(zi.y, u[k].y, pa);
            pa = fmaf(zi.z, u[k].z, pa);
            pa = fmaf(zi.w, u[k].w, pa);
            float pb = zi.x * v[k].x;
            pb = fmaf(zi.y, v[k].y, pb);
            pb = fmaf(zi.z, v[k].z, pb);
            pb = fmaf(zi.w, v[k].w, pb);
            const float r1 = sum8(pa);   // raw int-basis sims1 (x su pending)
            const float r2 = sum8(pb);   // raw int-basis sims2 (x sv pending)
            const int q = i * 4 + k;
            d1a = fmaf(wA[q], r1, d1a);
            d1b = fmaf(wB[q], r1, d1b);
            d2a = fmaf(wA[q], r2, d2a);
            d2b = fmaf(wB[q], r2, d2b);
        }
    }

    const float o1a = fast_tanh(fmaf( 2.0f * su, d1a, bb.x));
    const float o1b = fast_tanh(fmaf( 2.0f * su, d1b, bb.y));
    const float o2a = fast_tanh(fmaf(-2.0f * sv, d2a, bb.x));
    const float o2b = fast_tanh(fmaf(-2.0f * sv, d2b, bb.y));

    *(float2*)(out + (size_t)pair * 16 + p0) = make_float2(o1a, o1b); // 64B/pair
    *(float2*)(out + (size_t)e2   * 16 + p0) = make_float2(o2a, o2b);
}

// ---- fallback (proven round-4/9 f32 kernel) if ws is too small -------------
__global__ __launch_bounds__(TPB) void sheaf_f32_kernel(
    const float* __restrict__ x, const float* __restrict__ Maps,
    const float* __restrict__ W1, const float* __restrict__ b1,
    const int* __restrict__ edge_index, const int* __restrict__ opp_idx,
    float* __restrict__ out, int E, int EHALF)
{
    const int tid  = threadIdx.x;
    const int l    = tid & 15;
    const int pair = (blockIdx.x * TPB + tid) >> 4;
    if (pair >= EHALF) return;
    const int s  = edge_index[pair];
    const int t  = edge_index[E + pair];
    const int e2 = opp_idx[pair];

    const float* xu = x + (size_t)s * 128 + 2 * l;
    const float* xv = x + (size_t)t * 128 + 2 * l;
    float2 u[4], v[4];
    #pragma unroll
    for (int d = 0; d < 4; ++d) {
        u[d] = *(const float2*)(xu + d * 32);
        v[d] = *(const float2*)(xv + d * 32);
    }
    const float4* M1p = (const float4*)(Maps + (size_t)pair * 16);
    const float4* M2p = (const float4*)(Maps + (size_t)e2   * 16);
    float4 m1[4], m2[4];
    #pragma unroll
    for (int i = 0; i < 4; ++i) { m1[i] = M1p[i]; m2[i] = M2p[i]; }
    float wr[16];
    {
        const float4* Wp = (const float4*)(W1 + l * 16);
        #pragma unroll
        for (int q4 = 0; q4 < 4; ++q4) {
            float4 w = Wp[q4];
            wr[q4*4+0] = w.x; wr[q4*4+1] = w.y; wr[q4*4+2] = w.z; wr[q4*4+3] = w.w;
        }
    }
    const float bias = b1[l];
    float2 Z[4];
    #pragma unroll
    for (int i = 0; i < 4; ++i) {
        float zx = m1[i].x * u[0].x;
        zx = fmaf(m1[i].y, u[1].x, zx);
        zx = fmaf(m1[i].z, u[2].x, zx);
        zx = fmaf(m1[i].w, u[3].x, zx);
        zx = fmaf(-m2[i].x, v[0].x, zx);
        zx = fmaf(-m2[i].y, v[1].x, zx);
        zx = fmaf(-m2[i].z, v[2].x, zx);
        zx = fmaf(-m2[i].w, v[3].x, zx);
        float zy = m1[i].x * u[0].y;
        zy = fmaf(m1[i].y, u[1].y, zy);
        zy = fmaf(m1[i].z, u[2].y, zy);
        zy = fmaf(m1[i].w, u[3].y, zy);
        zy = fmaf(-m2[i].x, v[0].y, zy);
        zy = fmaf(-m2[i].y, v[1].y, zy);
        zy = fmaf(-m2[i].z, v[2].y, zy);
        zy = fmaf(-m2[i].w, v[3].y, zy);
        Z[i] = make_float2(zx, zy);
    }
    float d1 = 0.f, d2 = 0.f;
    #pragma unroll
    for (int i = 0; i < 4; ++i) {
        #pragma unroll
        for (int k = 0; k < 4; ++k) {
            float pa = Z[i].x * u[k].x;
            pa = fmaf(Z[i].y, u[k].y, pa);
            float pb = Z[i].x * v[k].x;
            pb = fmaf(Z[i].y, v[k].y, pb);
            const float r1 = rowsum16(pa);
            const float r2 = rowsum16(pb);
            const int q = i * 4 + k;
            d1 = fmaf(wr[q], r1, d1);
            d2 = fmaf(wr[q], r2, d2);
        }
    }
    const float a1 = fmaf( 2.0f, d1, bias);
    const float a2 = fmaf(-2.0f, d2, bias);
    out[(size_t)pair * 16 + l] = fast_tanh(a1);
    out[(size_t)e2   * 16 + l] = fast_tanh(a2);
}

extern "C" void kernel_launch(void* const* d_in, const int* in_sizes, int n_in,
                              void* d_out, int out_size, void* d_ws, size_t ws_size,
                              hipStream_t stream) {
    const float* x          = (const float*)d_in[0];
    const float* Maps       = (const float*)d_in[1];
    const float* W1         = (const float*)d_in[2];
    const float* b1         = (const float*)d_in[3];
    const int*   edge_index = (const int*)d_in[4];
    const int*   opp_idx    = (const int*)d_in[5];

    const int N     = in_sizes[0] / 128;
    const int E     = in_sizes[5];
    const int EHALF = E / 2;

    const size_t q_bytes = (size_t)N * 16 * sizeof(uint4);  // 256 B/node
    const size_t ws_need = q_bytes + (size_t)N * sizeof(float);

    if (ws_size >= ws_need) {
        uint4* xq     = (uint4*)d_ws;
        float* xscale = (float*)((char*)d_ws + q_bytes);
        const int pack_blocks = (N * 16 + TPB - 1) / TPB;
        pack_q16_kernel<<<pack_blocks, TPB, 0, stream>>>(x, xq, xscale, N);
        const int pair_blocks = (EHALF + PAIRS_PER_BLOCK - 1) / PAIRS_PER_BLOCK;
        sheaf_q8_kernel<<<pair_blocks, TPB, 0, stream>>>(
            xq, xscale, Maps, W1, b1, edge_index, opp_idx, (float*)d_out, E, EHALF);
    } else {
        const int pair_blocks = (EHALF + 15) / 16;
        sheaf_f32_kernel<<<pair_blocks, TPB, 0, stream>>>(
            x, Maps, W1, b1, edge_index, opp_idx, (float*)d_out, E, EHALF);
    }
}

// Round 14
// 58.070 us; speedup vs baseline: 1.2035x; 1.2035x over previous
//
#include <hip/hip_runtime.h>

constexpr int TPB = 256;
constexpr int PPB = 32;   // pairs per block: 16 rows x 2 pairs (A: +row, B: +16+row)

__device__ __forceinline__ float fast_tanh(float v) {
    // tanh(x) = 1 - 2/(exp(2x)+1); exact at +/-inf, ~ulp-level error
    float ex = __expf(2.0f * v);
    return 1.0f - 2.0f * __builtin_amdgcn_rcpf(ex + 1.0f);
}

template <int CTRL>
__device__ __forceinline__ float dppadd(float x) {
    return x + __int_as_float(__builtin_amdgcn_update_dpp(
        0, __float_as_int(x), CTRL, 0xf, 0xf, true));
}
template <int CTRL>
__device__ __forceinline__ float dppmax(float x) {
    return fmaxf(x, __int_as_float(__builtin_amdgcn_update_dpp(
        0, __float_as_int(x), CTRL, 0xf, 0xf, true)));
}

// all-lanes reduce within each 16-lane DPP row (rotate-and-combine butterfly)
__device__ __forceinline__ float rowsum16(float x) {
    x = dppadd<0x128>(x); x = dppadd<0x124>(x);
    x = dppadd<0x122>(x); x = dppadd<0x121>(x);
    return x;
}
__device__ __forceinline__ float rowmax16(float x) {
    x = dppmax<0x128>(x); x = dppmax<0x124>(x);
    x = dppmax<0x122>(x); x = dppmax<0x121>(x);
    return x;
}

__device__ __forceinline__ float2 unpack_q(unsigned int w) {
    // low/high int16 -> float (int-valued); compiler emits bfe/ashr + cvt
    return make_float2((float)((int)(w << 16) >> 16), (float)((int)w >> 16));
}

// ---- pack kernel: x (N,4,32) f32 -> int16 with per-node scale --------------
// Lane-transposed: lane l's 8 values (d=0..3, h-cols {2l,2l+1}) = one uint4.
__global__ __launch_bounds__(TPB) void pack_q16_kernel(
    const float* __restrict__ x, uint4* __restrict__ xq,
    float* __restrict__ xscale, int N)
{
    const int tid  = blockIdx.x * TPB + threadIdx.x;
    const int node = tid >> 4, l = tid & 15;
    if (node >= N) return;
    const float* xr = x + (size_t)node * 128 + 2 * l;
    float2 f[4]; float m = 0.f;
    #pragma unroll
    for (int d = 0; d < 4; ++d) {
        f[d] = *(const float2*)(xr + d * 32);       // coalesced 8B/lane
        m = fmaxf(m, fmaxf(fabsf(f[d].x), fabsf(f[d].y)));
    }
    m = rowmax16(m);                                 // node absmax (all 16 lanes)
    const float inv = m > 0.f ? 32767.0f / m : 0.f;
    unsigned int w[4];
    #pragma unroll
    for (int d = 0; d < 4; ++d) {
        int ix = (int)rintf(f[d].x * inv);
        int iy = (int)rintf(f[d].y * inv);
        w[d] = ((unsigned int)ix & 0xFFFFu) | ((unsigned int)iy << 16);
    }
    xq[(size_t)node * 16 + l] = make_uint4(w[0], w[1], w[2], w[3]);  // coalesced
    if (l == 0) xscale[node] = m * (1.0f / 32767.0f);
}

// ---- main kernel: round-11 math, TWO pairs per 16-lane row -----------------
// Pair B's idx + x-gathers are issued BEFORE pair A's compute, hiding B's
// ~900cy gather chain under A's ~700cy of VALU work.
__global__ __launch_bounds__(TPB) void sheaf_q16x2_kernel(
    const uint4* __restrict__ xq,         // (N, 16) packed int16
    const float* __restrict__ xscale,     // (N,)
    const float* __restrict__ Maps,       // (E, 4, 4)
    const float* __restrict__ W1,         // (16, 16)
    const float* __restrict__ b1,         // (16,)
    const int*   __restrict__ edge_index, // (2, E)
    const int*   __restrict__ opp_idx,    // (E,)
    float*       __restrict__ out,        // (E, 4, 4)
    int E, int EHALF)
{
    const int tid = threadIdx.x;
    const int l   = tid & 15;
    const int row = tid >> 4;
    const int base = blockIdx.x * PPB;
    const int pairA = base + row;
    const int pairB = base + 16 + row;
    if (pairA >= EHALF) return;
    const bool haveB = pairB < EHALF;

    // ---- issue ALL gathers up front (A and B chains overlap) ----
    const int sA  = edge_index[pairA];
    const int tA  = edge_index[E + pairA];
    const int eA  = opp_idx[pairA];
    const int pB  = haveB ? pairB : pairA;
    const int sB  = edge_index[pB];
    const int tB  = edge_index[E + pB];
    const int eB  = opp_idx[pB];

    const uint4 quA = xq[(size_t)sA * 16 + l];
    const uint4 qvA = xq[(size_t)tA * 16 + l];
    const uint4 quB = xq[(size_t)sB * 16 + l];
    const uint4 qvB = xq[(size_t)tB * 16 + l];
    const float suA = xscale[sA], svA = xscale[tA];
    const float suB = xscale[sB], svB = xscale[tB];

    // lane-owned W1 row + bias (live across both pairs)
    float wr[16];
    {
        const float4* Wp = (const float4*)(W1 + l * 16);
        #pragma unroll
        for (int q4 = 0; q4 < 4; ++q4) {
            float4 w = Wp[q4];
            wr[q4*4+0] = w.x; wr[q4*4+1] = w.y; wr[q4*4+2] = w.z; wr[q4*4+3] = w.w;
        }
    }
    const float bias = b1[l];

    auto compute = [&](int pair, int e2, const uint4& qu, const uint4& qv,
                       float su, float sv) {
        // unpack to true units
        float2 u[4], v[4];
        u[0] = unpack_q(qu.x); u[1] = unpack_q(qu.y);
        u[2] = unpack_q(qu.z); u[3] = unpack_q(qu.w);
        v[0] = unpack_q(qv.x); v[1] = unpack_q(qv.y);
        v[2] = unpack_q(qv.z); v[3] = unpack_q(qv.w);
        #pragma unroll
        for (int d = 0; d < 4; ++d) {
            u[d].x *= su; u[d].y *= su;
            v[d].x *= sv; v[d].y *= sv;
        }

        const float4* M1p = (const float4*)(Maps + (size_t)pair * 16);
        const float4* M2p = (const float4*)(Maps + (size_t)e2   * 16);
        float4 m1[4], m2[4];
        #pragma unroll
        for (int i = 0; i < 4; ++i) { m1[i] = M1p[i]; m2[i] = M2p[i]; }

        // Z rows over the lane's 2 h-cols (true units)
        float2 Z[4];
        #pragma unroll
        for (int i = 0; i < 4; ++i) {
            float zx = m1[i].x * u[0].x;
            zx = fmaf(m1[i].y, u[1].x, zx);
            zx = fmaf(m1[i].z, u[2].x, zx);
            zx = fmaf(m1[i].w, u[3].x, zx);
            zx = fmaf(-m2[i].x, v[0].x, zx);
            zx = fmaf(-m2[i].y, v[1].x, zx);
            zx = fmaf(-m2[i].z, v[2].x, zx);
            zx = fmaf(-m2[i].w, v[3].x, zx);
            float zy = m1[i].x * u[0].y;
            zy = fmaf(m1[i].y, u[1].y, zy);
            zy = fmaf(m1[i].z, u[2].y, zy);
            zy = fmaf(m1[i].w, u[3].y, zy);
            zy = fmaf(-m2[i].x, v[0].y, zy);
            zy = fmaf(-m2[i].y, v[1].y, zy);
            zy = fmaf(-m2[i].z, v[2].y, zy);
            zy = fmaf(-m2[i].w, v[3].y, zy);
            Z[i] = make_float2(zx, zy);
        }

        // per-(i,k) partials -> DPP all-reduce -> fused linear
        float d1 = 0.f, d2 = 0.f;
        #pragma unroll
        for (int i = 0; i < 4; ++i) {
            #pragma unroll
            for (int k = 0; k < 4; ++k) {
                float pa = Z[i].x * u[k].x;
                pa = fmaf(Z[i].y, u[k].y, pa);
                float pb = Z[i].x * v[k].x;
                pb = fmaf(Z[i].y, v[k].y, pb);
                const float r1 = rowsum16(pa);
                const float r2 = rowsum16(pb);
                const int q = i * 4 + k;
                d1 = fmaf(wr[q], r1, d1);
                d2 = fmaf(wr[q], r2, d2);
            }
        }
        const float a1 = fmaf( 2.0f, d1, bias);
        const float a2 = fmaf(-2.0f, d2, bias);

        out[(size_t)pair * 16 + l] = fast_tanh(a1);   // 64B contiguous per pair
        out[(size_t)e2   * 16 + l] = fast_tanh(a2);
    };

    compute(pairA, eA, quA, qvA, suA, svA);
    if (haveB) compute(pairB, eB, quB, qvB, suB, svB);
}

// ---- fallback (proven round-4/9 f32 kernel) if ws is too small -------------
__global__ __launch_bounds__(TPB) void sheaf_f32_kernel(
    const float* __restrict__ x, const float* __restrict__ Maps,
    const float* __restrict__ W1, const float* __restrict__ b1,
    const int* __restrict__ edge_index, const int* __restrict__ opp_idx,
    float* __restrict__ out, int E, int EHALF)
{
    const int tid  = threadIdx.x;
    const int l    = tid & 15;
    const int pair = (blockIdx.x * TPB + tid) >> 4;
    if (pair >= EHALF) return;
    const int s  = edge_index[pair];
    const int t  = edge_index[E + pair];
    const int e2 = opp_idx[pair];

    const float* xu = x + (size_t)s * 128 + 2 * l;
    const float* xv = x + (size_t)t * 128 + 2 * l;
    float2 u[4], v[4];
    #pragma unroll
    for (int d = 0; d < 4; ++d) {
        u[d] = *(const float2*)(xu + d * 32);
        v[d] = *(const float2*)(xv + d * 32);
    }
    const float4* M1p = (const float4*)(Maps + (size_t)pair * 16);
    const float4* M2p = (const float4*)(Maps + (size_t)e2   * 16);
    float4 m1[4], m2[4];
    #pragma unroll
    for (int i = 0; i < 4; ++i) { m1[i] = M1p[i]; m2[i] = M2p[i]; }
    float wr[16];
    {
        const float4* Wp = (const float4*)(W1 + l * 16);
        #pragma unroll
        for (int q4 = 0; q4 < 4; ++q4) {
            float4 w = Wp[q4];
            wr[q4*4+0] = w.x; wr[q4*4+1] = w.y; wr[q4*4+2] = w.z; wr[q4*4+3] = w.w;
        }
    }
    const float bias = b1[l];
    float2 Z[4];
    #pragma unroll
    for (int i = 0; i < 4; ++i) {
        float zx = m1[i].x * u[0].x;
        zx = fmaf(m1[i].y, u[1].x, zx);
        zx = fmaf(m1[i].z, u[2].x, zx);
        zx = fmaf(m1[i].w, u[3].x, zx);
        zx = fmaf(-m2[i].x, v[0].x, zx);
        zx = fmaf(-m2[i].y, v[1].x, zx);
        zx = fmaf(-m2[i].z, v[2].x, zx);
        zx = fmaf(-m2[i].w, v[3].x, zx);
        float zy = m1[i].x * u[0].y;
        zy = fmaf(m1[i].y, u[1].y, zy);
        zy = fmaf(m1[i].z, u[2].y, zy);
        zy = fmaf(m1[i].w, u[3].y, zy);
        zy = fmaf(-m2[i].x, v[0].y, zy);
        zy = fmaf(-m2[i].y, v[1].y, zy);
        zy = fmaf(-m2[i].z, v[2].y, zy);
        zy = fmaf(-m2[i].w, v[3].y, zy);
        Z[i] = make_float2(zx, zy);
    }
    float d1 = 0.f, d2 = 0.f;
    #pragma unroll
    for (int i = 0; i < 4; ++i) {
        #pragma unroll
        for (int k = 0; k < 4; ++k) {
            float pa = Z[i].x * u[k].x;
            pa = fmaf(Z[i].y, u[k].y, pa);
            float pb = Z[i].x * v[k].x;
            pb = fmaf(Z[i].y, v[k].y, pb);
            const float r1 = rowsum16(pa);
            const float r2 = rowsum16(pb);
            const int q = i * 4 + k;
            d1 = fmaf(wr[q], r1, d1);
            d2 = fmaf(wr[q], r2, d2);
        }
    }
    const float a1 = fmaf( 2.0f, d1, bias);
    const float a2 = fmaf(-2.0f, d2, bias);
    out[(size_t)pair * 16 + l] = fast_tanh(a1);
    out[(size_t)e2   * 16 + l] = fast_tanh(a2);
}

extern "C" void kernel_launch(void* const* d_in, const int* in_sizes, int n_in,
                              void* d_out, int out_size, void* d_ws, size_t ws_size,
                              hipStream_t stream) {
    const float* x          = (const float*)d_in[0];
    const float* Maps       = (const float*)d_in[1];
    const float* W1         = (const float*)d_in[2];
    const float* b1         = (const float*)d_in[3];
    const int*   edge_index = (const int*)d_in[4];
    const int*   opp_idx    = (const int*)d_in[5];

    const int N     = in_sizes[0] / 128;
    const int E     = in_sizes[5];
    const int EHALF = E / 2;

    const size_t q_bytes = (size_t)N * 16 * sizeof(uint4);  // 256 B/node
    const size_t ws_need = q_bytes + (size_t)N * sizeof(float);

    if (ws_size >= ws_need) {
        uint4* xq     = (uint4*)d_ws;
        float* xscale = (float*)((char*)d_ws + q_bytes);
        const int pack_blocks = (N * 16 + TPB - 1) / TPB;
        pack_q16_kernel<<<pack_blocks, TPB, 0, stream>>>(x, xq, xscale, N);
        const int pair_blocks = (EHALF + PPB - 1) / PPB;
        sheaf_q16x2_kernel<<<pair_blocks, TPB, 0, stream>>>(
            xq, xscale, Maps, W1, b1, edge_index, opp_idx, (float*)d_out, E, EHALF);
    } else {
        const int pair_blocks = (EHALF + 15) / 16;
        sheaf_f32_kernel<<<pair_blocks, TPB, 0, stream>>>(
            x, Maps, W1, b1, edge_index, opp_idx, (float*)d_out, E, EHALF);
    }
}